// Round 1
// baseline (1287.129 us; speedup 1.0000x reference)
//
#include <hip/hip_runtime.h>
#include <math.h>

typedef __attribute__((ext_vector_type(8))) short short8;
typedef __attribute__((ext_vector_type(4))) float floatx4;

#define MFMA16(a, b, c) __builtin_amdgcn_mfma_f32_16x16x32_bf16((a), (b), (c), 0, 0, 0)

__device__ __forceinline__ unsigned short f2bf(float x) {
    unsigned int u = __float_as_uint(x);
    u += 0x7fffu + ((u >> 16) & 1u);   // round-to-nearest-even
    return (unsigned short)(u >> 16);
}

__device__ __forceinline__ short8 lds8(const unsigned short* p) {
    return *reinterpret_cast<const short8*>(p);
}

// ---------------- prep: fp32 -> bf16 convert (vectorized) ----------------
__global__ void cvt_bf16(const float* __restrict__ src, unsigned short* __restrict__ dst, int n4) {
    int i = blockIdx.x * blockDim.x + threadIdx.x;
    if (i >= n4) return;
    float4 v = reinterpret_cast<const float4*>(src)[i];
    ushort4 o;
    o.x = f2bf(v.x); o.y = f2bf(v.y); o.z = f2bf(v.z); o.w = f2bf(v.w);
    reinterpret_cast<ushort4*>(dst)[i] = o;
}

// ---------------- prep: K window convert + V window transpose ----------------
// k_cache/v_cache: (B=2, KV=8, Tc=4096, DH=64) fp32. Window = rows 3072..4095.
// Kw:  (b,kv, s(1024), d(64))  bf16
// Vt:  (b,kv, d(64), s(1024))  bf16
__global__ void prep_kv(const float* __restrict__ kc, const float* __restrict__ vc,
                        unsigned short* __restrict__ Kw, unsigned short* __restrict__ Vt) {
    int i = blockIdx.x * blockDim.x + threadIdx.x;   // 0 .. 262143
    int d4  = (i & 15) * 4;
    int s   = (i >> 4) & 1023;
    int bkv = i >> 14;                               // 0..15
    size_t src = ((size_t)bkv * 4096 + 3072 + s) * 64 + d4;
    float4 kv = *reinterpret_cast<const float4*>(kc + src);
    float4 vv = *reinterpret_cast<const float4*>(vc + src);
    ushort4 ko;
    ko.x = f2bf(kv.x); ko.y = f2bf(kv.y); ko.z = f2bf(kv.z); ko.w = f2bf(kv.w);
    *reinterpret_cast<ushort4*>(Kw + ((size_t)bkv * 1024 + s) * 64 + d4) = ko;
    unsigned short vo[4] = { f2bf(vv.x), f2bf(vv.y), f2bf(vv.z), f2bf(vv.w) };
#pragma unroll
    for (int m = 0; m < 4; ++m)
        Vt[((size_t)bkv * 64 + d4 + m) * 1024 + s] = vo[m];
}

// ---------------- bf16 MFMA GEMM: C[M,N] = A[M,K] * Bt[N,K]^T ----------------
// M=8192, N=2048, K=2048. 128x128 tile, BK=32, 4 waves (2x2 of 64x64).
// EPI==0: RoPE epilogue, write Q (b,h,t,d) bf16.  EPI==1: write fp32 row-major.
template <int EPI>
__global__ __launch_bounds__(256)
void gemm_bt(const unsigned short* __restrict__ A,
             const unsigned short* __restrict__ Bt,
             float* __restrict__ Cf,
             unsigned short* __restrict__ Cb) {
    constexpr int K = 2048;
    __shared__ unsigned short As[128 * 32];
    __shared__ unsigned short Bs[128 * 32];

    const int tid  = threadIdx.x;
    const int lane = tid & 63;
    const int l15  = lane & 15;
    const int quad = lane >> 4;
    const int wid  = tid >> 6;
    const int wm   = (wid & 1) * 64;
    const int wn   = (wid >> 1) * 64;

    const int bn = blockIdx.x & 15;   // N/128 = 16
    const int bm = blockIdx.x >> 4;   // M/128 = 64

    const int r1 = tid >> 2;          // 0..63
    const int r2 = r1 + 64;
    const int c8 = (tid & 3) * 8;     // 0,8,16,24

    const unsigned short* Arow1 = A  + (size_t)(bm * 128 + r1) * K + c8;
    const unsigned short* Arow2 = A  + (size_t)(bm * 128 + r2) * K + c8;
    const unsigned short* Brow1 = Bt + (size_t)(bn * 128 + r1) * K + c8;
    const unsigned short* Brow2 = Bt + (size_t)(bn * 128 + r2) * K + c8;

    floatx4 zero = {0.f, 0.f, 0.f, 0.f};
    floatx4 acc[4][4];
#pragma unroll
    for (int i = 0; i < 4; ++i)
#pragma unroll
        for (int j = 0; j < 4; ++j) acc[i][j] = zero;

    for (int k0 = 0; k0 < K; k0 += 32) {
        short8 a1 = lds8(Arow1 + k0);
        short8 a2 = lds8(Arow2 + k0);
        short8 b1 = lds8(Brow1 + k0);
        short8 b2 = lds8(Brow2 + k0);
        __syncthreads();
        *reinterpret_cast<short8*>(&As[r1 * 32 + c8]) = a1;
        *reinterpret_cast<short8*>(&As[r2 * 32 + c8]) = a2;
        *reinterpret_cast<short8*>(&Bs[r1 * 32 + c8]) = b1;
        *reinterpret_cast<short8*>(&Bs[r2 * 32 + c8]) = b2;
        __syncthreads();
        short8 af[4], bf[4];
#pragma unroll
        for (int i = 0; i < 4; ++i) af[i] = lds8(&As[(wm + i * 16 + l15) * 32 + quad * 8]);
#pragma unroll
        for (int j = 0; j < 4; ++j) bf[j] = lds8(&Bs[(wn + j * 16 + l15) * 32 + quad * 8]);
#pragma unroll
        for (int i = 0; i < 4; ++i)
#pragma unroll
            for (int j = 0; j < 4; ++j)
                acc[i][j] = MFMA16(af[i], bf[j], acc[i][j]);
    }

#pragma unroll
    for (int i = 0; i < 4; ++i) {
#pragma unroll
        for (int j = 0; j < 4; ++j) {
#pragma unroll
            for (int r = 0; r < 4; ++r) {
                int row = bm * 128 + wm + i * 16 + quad * 4 + r;
                int col = bn * 128 + wn + j * 16 + l15;
                float v = acc[i][j][r];
                if (EPI == 0) {
                    float p = __shfl_xor(v, 1);   // partner element of the RoPE pair
                    int t = row & 4095, b = row >> 12;
                    int h = col >> 6, d = col & 63;
                    float f = (float)t * exp2f(-(float)(d >> 1) * 0.41524101186092f);
                    float sn, cs;
                    sincosf(f, &sn, &cs);
                    float o = (d & 1) ? (p * sn + v * cs) : (v * cs - p * sn);
                    Cb[((size_t)((b * 32 + h) * 4096 + t)) * 64 + d] = f2bf(o);
                } else {
                    Cf[(size_t)row * 2048 + col] = v;
                }
            }
        }
    }
}

// ---------------- flash attention over 1024-key window ----------------
// grid: (b*32+h)*64 + qtile  (4096 blocks), 256 thr = 4 waves, wave = 16 queries.
// Mask semantics (per reference): window index s (0..1023) allowed iff s <= t.
__global__ __launch_bounds__(256)
void attn(const unsigned short* __restrict__ Q,
          const unsigned short* __restrict__ Kw,
          const unsigned short* __restrict__ Vt,
          unsigned short* __restrict__ O) {
    const int blk   = blockIdx.x;
    const int qtile = blk & 63;
    const int bh    = blk >> 6;
    const int h     = bh & 31;
    const int b     = bh >> 5;
    const int kvh   = h >> 2;

    const int tid  = threadIdx.x;
    const int lane = tid & 63;
    const int l15  = lane & 15;
    const int quad = lane >> 4;
    const int wid  = tid >> 6;
    const int qt0  = qtile * 64 + wid * 16;

    const unsigned short* Qp = Q  + ((size_t)bh * 4096 + qt0) * 64;
    const unsigned short* Kp = Kw + (size_t)(b * 8 + kvh) * 1024 * 64;
    const unsigned short* Vp = Vt + (size_t)(b * 8 + kvh) * 64 * 1024;

    __shared__ unsigned short Pbuf[4][16 * 32];
    unsigned short* pb = Pbuf[wid];

    short8 qa0 = lds8(&Qp[l15 * 64 + quad * 8]);
    short8 qa1 = lds8(&Qp[l15 * 64 + 32 + quad * 8]);

    floatx4 o0 = {0,0,0,0}, o1 = {0,0,0,0}, o2 = {0,0,0,0}, o3 = {0,0,0,0};
    float mrow[4] = {-INFINITY, -INFINITY, -INFINITY, -INFINITY};
    float lrow[4] = {0.f, 0.f, 0.f, 0.f};

    const int qhi    = qt0 + 15;
    const int nkeys  = (qhi < 1023 ? qhi : 1023) + 1;
    const int ntiles = (nkeys + 31) >> 5;

    for (int kt = 0; kt < ntiles; ++kt) {
        const int s0 = kt << 5;
        floatx4 sA = {0,0,0,0}, sB = {0,0,0,0};
        {
            const unsigned short* kp0 = Kp + (size_t)(s0 + l15) * 64 + quad * 8;
            const unsigned short* kp1 = kp0 + 16 * 64;
            short8 k00 = lds8(kp0);
            short8 k01 = lds8(kp0 + 32);
            short8 k10 = lds8(kp1);
            short8 k11 = lds8(kp1 + 32);
            sA = MFMA16(qa0, k00, sA);
            sA = MFMA16(qa1, k01, sA);
            sB = MFMA16(qa0, k10, sB);
            sB = MFMA16(qa1, k11, sB);
        }
        float alpha[4];
#pragma unroll
        for (int r = 0; r < 4; ++r) {
            const int q = qt0 + quad * 4 + r;
            float x0 = sA[r] * 0.125f;
            float x1 = sB[r] * 0.125f;
            if (s0 + l15 > q)      x0 = -INFINITY;
            if (s0 + 16 + l15 > q) x1 = -INFINITY;
            float mt = fmaxf(x0, x1);
#pragma unroll
            for (int off = 8; off >= 1; off >>= 1) mt = fmaxf(mt, __shfl_xor(mt, off));
            const float mnew = fmaxf(mrow[r], mt);
            alpha[r] = expf(mrow[r] - mnew);
            mrow[r]  = mnew;
            float p0 = expf(x0 - mnew);
            float p1 = expf(x1 - mnew);
            float ps = p0 + p1;
#pragma unroll
            for (int off = 8; off >= 1; off >>= 1) ps += __shfl_xor(ps, off);
            lrow[r] = lrow[r] * alpha[r] + ps;
            pb[(quad * 4 + r) * 32 + l15]      = f2bf(p0);
            pb[(quad * 4 + r) * 32 + 16 + l15] = f2bf(p1);
        }
#pragma unroll
        for (int r = 0; r < 4; ++r) {
            o0[r] *= alpha[r]; o1[r] *= alpha[r]; o2[r] *= alpha[r]; o3[r] *= alpha[r];
        }
        __asm__ volatile("" ::: "memory");     // keep P writes before the A-layout read
        short8 pa = lds8(&pb[l15 * 32 + quad * 8]);
        __asm__ volatile("" ::: "memory");     // keep read before next iter's writes
        const unsigned short* vbase = Vp + s0 + quad * 8;
        o0 = MFMA16(pa, lds8(vbase + (size_t)(l15)      * 1024), o0);
        o1 = MFMA16(pa, lds8(vbase + (size_t)(16 + l15) * 1024), o1);
        o2 = MFMA16(pa, lds8(vbase + (size_t)(32 + l15) * 1024), o2);
        o3 = MFMA16(pa, lds8(vbase + (size_t)(48 + l15) * 1024), o3);
    }

    // write O[b][t][h*64+d] as bf16 (input of GEMM3)
    unsigned short* Ob = O + (size_t)b * 4096 * 2048 + h * 64;
#pragma unroll
    for (int r = 0; r < 4; ++r) {
        const int q = qt0 + quad * 4 + r;
        const float inv = 1.f / lrow[r];
        unsigned short* op = Ob + (size_t)q * 2048 + l15;
        op[0]  = f2bf(o0[r] * inv);
        op[16] = f2bf(o1[r] * inv);
        op[32] = f2bf(o2[r] * inv);
        op[48] = f2bf(o3[r] * inv);
    }
}

// ---------------- launch ----------------
extern "C" void kernel_launch(void* const* d_in, const int* in_sizes, int n_in,
                              void* d_out, int out_size, void* d_ws, size_t ws_size,
                              hipStream_t stream) {
    const float* x  = (const float*)d_in[0];
    const float* kc = (const float*)d_in[1];
    const float* vc = (const float*)d_in[2];
    const float* Wq = (const float*)d_in[3];
    const float* Wo = (const float*)d_in[4];
    float* out = (float*)d_out;

    char* ws = (char*)d_ws;
    unsigned short* Xb  = (unsigned short*)(ws);              // 33,554,432 B (reused as O)
    unsigned short* Qb  = (unsigned short*)(ws + 33554432);   // 33,554,432 B
    unsigned short* Wqb = (unsigned short*)(ws + 67108864);   //  8,388,608 B
    unsigned short* Wob = (unsigned short*)(ws + 75497472);   //  8,388,608 B
    unsigned short* Kwb = (unsigned short*)(ws + 83886080);   //  2,097,152 B
    unsigned short* Vtb = (unsigned short*)(ws + 85983232);   //  2,097,152 B

    cvt_bf16<<<16384, 256, 0, stream>>>(x,  Xb,  4194304);    // X:  16,777,216 elems
    cvt_bf16<<<4096,  256, 0, stream>>>(Wq, Wqb, 1048576);    // Wq:  4,194,304
    cvt_bf16<<<4096,  256, 0, stream>>>(Wo, Wob, 1048576);    // Wo:  4,194,304
    prep_kv<<<1024, 256, 0, stream>>>(kc, vc, Kwb, Vtb);

    gemm_bt<0><<<1024, 256, 0, stream>>>(Xb, Wqb, nullptr, Qb);   // Q + RoPE
    attn<<<4096, 256, 0, stream>>>(Qb, Kwb, Vtb, Xb);             // O -> Xb
    gemm_bt<1><<<1024, 256, 0, stream>>>(Xb, Wob, out, nullptr);  // out proj
}

// Round 2
// 852.341 us; speedup vs baseline: 1.5101x; 1.5101x over previous
//
#include <hip/hip_runtime.h>
#include <math.h>

typedef __attribute__((ext_vector_type(8))) short short8;
typedef __attribute__((ext_vector_type(4))) float floatx4;

#define MFMA16(a, b, c) __builtin_amdgcn_mfma_f32_16x16x32_bf16((a), (b), (c), 0, 0, 0)

__device__ __forceinline__ unsigned short f2bf(float x) {
    unsigned int u = __float_as_uint(x);
    u += 0x7fffu + ((u >> 16) & 1u);   // round-to-nearest-even
    return (unsigned short)(u >> 16);
}

__device__ __forceinline__ short8 lds8(const unsigned short* p) {
    return *reinterpret_cast<const short8*>(p);
}

// async global->LDS, 16B per lane; LDS dest = wave-uniform base + lane*16
__device__ __forceinline__ void g2l16(const unsigned short* g, unsigned short* l) {
    __builtin_amdgcn_global_load_lds(
        (const __attribute__((address_space(1))) unsigned int*)g,
        (__attribute__((address_space(3))) unsigned int*)l,
        16, 0, 0);
}

// ---------------- prep: fp32 -> bf16 convert (vectorized) ----------------
__global__ void cvt_bf16(const float* __restrict__ src, unsigned short* __restrict__ dst, int n4) {
    int i = blockIdx.x * blockDim.x + threadIdx.x;
    if (i >= n4) return;
    float4 v = reinterpret_cast<const float4*>(src)[i];
    ushort4 o;
    o.x = f2bf(v.x); o.y = f2bf(v.y); o.z = f2bf(v.z); o.w = f2bf(v.w);
    reinterpret_cast<ushort4*>(dst)[i] = o;
}

// ---------------- prep: K window convert (coalesced both sides) ----------------
// k_cache: (B=2, KV=8, Tc=4096, DH=64) fp32, window rows 3072..4095.
// Kw: (b,kv, s(1024), d(64)) bf16
__global__ void prep_k(const float* __restrict__ kc, unsigned short* __restrict__ Kw) {
    int i = blockIdx.x * blockDim.x + threadIdx.x;   // 0 .. 262143
    int d4  = (i & 15) * 4;
    int s   = (i >> 4) & 1023;
    int bkv = i >> 14;
    size_t src = ((size_t)bkv * 4096 + 3072 + s) * 64 + d4;
    float4 kv = *reinterpret_cast<const float4*>(kc + src);
    ushort4 ko;
    ko.x = f2bf(kv.x); ko.y = f2bf(kv.y); ko.z = f2bf(kv.z); ko.w = f2bf(kv.w);
    *reinterpret_cast<ushort4*>(Kw + ((size_t)bkv * 1024 + s) * 64 + d4) = ko;
}

// ---------------- prep: V window transpose via LDS tile ----------------
// Vt: (b,kv, d(64), s(1024)) bf16.  grid = 16 bkv x 16 s-tiles, 256 thr.
__global__ void prep_v(const float* __restrict__ vc, unsigned short* __restrict__ Vt) {
    __shared__ unsigned short tl[64][72];   // pitch 144B: 16B-aligned rows
    const int bkv = blockIdx.x >> 4;
    const int s0  = (blockIdx.x & 15) * 64;
    const int t   = threadIdx.x;
    const int sl  = t >> 2;            // 0..63 (s within tile)
    const int dq  = (t & 3) * 16;      // d quarter
    const float* src = vc + ((size_t)bkv * 4096 + 3072 + s0 + sl) * 64 + dq;
    float4 v0 = reinterpret_cast<const float4*>(src)[0];
    float4 v1 = reinterpret_cast<const float4*>(src)[1];
    float4 v2 = reinterpret_cast<const float4*>(src)[2];
    float4 v3 = reinterpret_cast<const float4*>(src)[3];
    tl[dq +  0][sl] = f2bf(v0.x); tl[dq +  1][sl] = f2bf(v0.y);
    tl[dq +  2][sl] = f2bf(v0.z); tl[dq +  3][sl] = f2bf(v0.w);
    tl[dq +  4][sl] = f2bf(v1.x); tl[dq +  5][sl] = f2bf(v1.y);
    tl[dq +  6][sl] = f2bf(v1.z); tl[dq +  7][sl] = f2bf(v1.w);
    tl[dq +  8][sl] = f2bf(v2.x); tl[dq +  9][sl] = f2bf(v2.y);
    tl[dq + 10][sl] = f2bf(v2.z); tl[dq + 11][sl] = f2bf(v2.w);
    tl[dq + 12][sl] = f2bf(v3.x); tl[dq + 13][sl] = f2bf(v3.y);
    tl[dq + 14][sl] = f2bf(v3.z); tl[dq + 15][sl] = f2bf(v3.w);
    __syncthreads();
    const int dl = t >> 2;             // d row
    const int sc = (t & 3) * 16;       // s chunk
    unsigned short* dst = Vt + ((size_t)bkv * 64 + dl) * 1024 + s0 + sc;
    short8 x0 = *reinterpret_cast<const short8*>(&tl[dl][sc]);
    short8 x1 = *reinterpret_cast<const short8*>(&tl[dl][sc + 8]);
    *reinterpret_cast<short8*>(dst)     = x0;
    *reinterpret_cast<short8*>(dst + 8) = x1;
}

// ---------------- bf16 MFMA GEMM (m97 structure): C = A[M,K] * Bt[N,K]^T ----------------
// M=8192, N=2048, K=2048. 128x128 tile, BK=32, 4 waves (2x2 of 64x64).
// Staging: global_load_lds width=16, no VGPR round-trip. Named accumulators.
// EPI==0: RoPE epilogue -> Q (b,h,t,d) bf16 (packed dword stores).
// EPI==1: fp32 row-major.
template <int EPI>
__global__ __launch_bounds__(256)
void gemm_bt(const unsigned short* __restrict__ A,
             const unsigned short* __restrict__ Bt,
             float* __restrict__ Cf,
             unsigned short* __restrict__ Cb) {
    constexpr int K = 2048;
    __shared__ unsigned short As[128 * 32];   // 8 KB, flat chunk c<->elem c*8
    __shared__ unsigned short Bs[128 * 32];

    const int tid  = threadIdx.x;
    const int lane = tid & 63;
    const int l15  = lane & 15;
    const int quad = lane >> 4;
    const int wid  = tid >> 6;
    const int wm   = (wid & 1) * 64;
    const int wn   = (wid >> 1) * 64;

    const int bn = blockIdx.x & 15;   // N/128 = 16
    const int bm = blockIdx.x >> 4;   // M/128 = 64

    // staging chunk c0 = tid (rows 0..63), c1 = tid+256 (rows 64..127)
    const int row0 = tid >> 2;
    const int kc8  = (tid & 3) * 8;
    const unsigned short* Ag0 = A  + (size_t)(bm * 128 + row0) * K + kc8;
    const unsigned short* Ag1 = Ag0 + (size_t)64 * K;
    const unsigned short* Bg0 = Bt + (size_t)(bn * 128 + row0) * K + kc8;
    const unsigned short* Bg1 = Bg0 + (size_t)64 * K;
    unsigned short* AsW0 = As + wid * 512;          // wave-uniform LDS bases
    unsigned short* AsW1 = As + 2048 + wid * 512;
    unsigned short* BsW0 = Bs + wid * 512;
    unsigned short* BsW1 = Bs + 2048 + wid * 512;

    floatx4 c00 = {0,0,0,0}, c01 = {0,0,0,0}, c02 = {0,0,0,0}, c03 = {0,0,0,0};
    floatx4 c10 = {0,0,0,0}, c11 = {0,0,0,0}, c12 = {0,0,0,0}, c13 = {0,0,0,0};
    floatx4 c20 = {0,0,0,0}, c21 = {0,0,0,0}, c22 = {0,0,0,0}, c23 = {0,0,0,0};
    floatx4 c30 = {0,0,0,0}, c31 = {0,0,0,0}, c32 = {0,0,0,0}, c33 = {0,0,0,0};

    for (int k0 = 0; k0 < K; k0 += 32) {
        __syncthreads();                       // prev iter's LDS reads done
        g2l16(Ag0 + k0, AsW0);
        g2l16(Ag1 + k0, AsW1);
        g2l16(Bg0 + k0, BsW0);
        g2l16(Bg1 + k0, BsW1);
        __syncthreads();                       // vmcnt(0) drain before barrier

        short8 a0 = lds8(&As[(wm +  0 + l15) * 32 + quad * 8]);
        short8 a1 = lds8(&As[(wm + 16 + l15) * 32 + quad * 8]);
        short8 a2 = lds8(&As[(wm + 32 + l15) * 32 + quad * 8]);
        short8 a3 = lds8(&As[(wm + 48 + l15) * 32 + quad * 8]);
        short8 b0 = lds8(&Bs[(wn +  0 + l15) * 32 + quad * 8]);
        short8 b1 = lds8(&Bs[(wn + 16 + l15) * 32 + quad * 8]);
        short8 b2 = lds8(&Bs[(wn + 32 + l15) * 32 + quad * 8]);
        short8 b3 = lds8(&Bs[(wn + 48 + l15) * 32 + quad * 8]);

        c00 = MFMA16(a0, b0, c00); c01 = MFMA16(a0, b1, c01);
        c02 = MFMA16(a0, b2, c02); c03 = MFMA16(a0, b3, c03);
        c10 = MFMA16(a1, b0, c10); c11 = MFMA16(a1, b1, c11);
        c12 = MFMA16(a1, b2, c12); c13 = MFMA16(a1, b3, c13);
        c20 = MFMA16(a2, b0, c20); c21 = MFMA16(a2, b1, c21);
        c22 = MFMA16(a2, b2, c22); c23 = MFMA16(a2, b3, c23);
        c30 = MFMA16(a3, b0, c30); c31 = MFMA16(a3, b1, c31);
        c32 = MFMA16(a3, b2, c32); c33 = MFMA16(a3, b3, c33);
    }

#define EPI_TILE(i, j, C) do {                                                  \
    _Pragma("unroll")                                                           \
    for (int r = 0; r < 4; ++r) {                                               \
        int row = bm * 128 + wm + (i) * 16 + quad * 4 + r;                      \
        int col = bn * 128 + wn + (j) * 16 + l15;                               \
        float v = (C)[r];                                                       \
        if (EPI == 0) {                                                         \
            float p = __shfl_xor(v, 1);                                         \
            int t = row & 4095, b = row >> 12;                                  \
            int hh = col >> 6, d = col & 63;                                    \
            float f = (float)t * exp2f(-(float)(d >> 1) * 0.41524101186092f);   \
            float sn, cs; sincosf(f, &sn, &cs);                                 \
            float o = (d & 1) ? (p * sn + v * cs) : (v * cs - p * sn);          \
            float po = __shfl_xor(o, 1);                                        \
            if (!(lane & 1)) {                                                  \
                unsigned int pk = (unsigned int)f2bf(o) |                       \
                                  ((unsigned int)f2bf(po) << 16);               \
                *reinterpret_cast<unsigned int*>(                               \
                    Cb + ((size_t)((b * 32 + hh) * 4096 + t)) * 64 + d) = pk;   \
            }                                                                   \
        } else {                                                                \
            Cf[(size_t)row * 2048 + col] = v;                                   \
        }                                                                       \
    }                                                                           \
} while (0)

    EPI_TILE(0, 0, c00); EPI_TILE(0, 1, c01); EPI_TILE(0, 2, c02); EPI_TILE(0, 3, c03);
    EPI_TILE(1, 0, c10); EPI_TILE(1, 1, c11); EPI_TILE(1, 2, c12); EPI_TILE(1, 3, c13);
    EPI_TILE(2, 0, c20); EPI_TILE(2, 1, c21); EPI_TILE(2, 2, c22); EPI_TILE(2, 3, c23);
    EPI_TILE(3, 0, c30); EPI_TILE(3, 1, c31); EPI_TILE(3, 2, c32); EPI_TILE(3, 3, c33);
#undef EPI_TILE
}

// ---------------- flash attention over 1024-key window ----------------
// grid: (b*32+h)*64 + qtile (4096 blocks), 256 thr = 4 waves, wave = 16 queries.
// Mask semantics (per reference): window index s (0..1023) allowed iff s <= t.
__global__ __launch_bounds__(256)
void attn(const unsigned short* __restrict__ Q,
          const unsigned short* __restrict__ Kw,
          const unsigned short* __restrict__ Vt,
          unsigned short* __restrict__ O) {
    const int blk   = blockIdx.x;
    const int qtile = blk & 63;
    const int bh    = blk >> 6;
    const int h     = bh & 31;
    const int b     = bh >> 5;
    const int kvh   = h >> 2;

    const int tid  = threadIdx.x;
    const int lane = tid & 63;
    const int l15  = lane & 15;
    const int quad = lane >> 4;
    const int wid  = tid >> 6;
    const int qt0  = qtile * 64 + wid * 16;

    const unsigned short* Qp = Q  + ((size_t)bh * 4096 + qt0) * 64;
    const unsigned short* Kp = Kw + (size_t)(b * 8 + kvh) * 1024 * 64;
    const unsigned short* Vp = Vt + (size_t)(b * 8 + kvh) * 64 * 1024;

    __shared__ unsigned short Pbuf[4][16 * 32];
    unsigned short* pb = Pbuf[wid];

    short8 qa0 = lds8(&Qp[l15 * 64 + quad * 8]);
    short8 qa1 = lds8(&Qp[l15 * 64 + 32 + quad * 8]);

    floatx4 o0 = {0,0,0,0}, o1 = {0,0,0,0}, o2 = {0,0,0,0}, o3 = {0,0,0,0};
    float mrow[4] = {-INFINITY, -INFINITY, -INFINITY, -INFINITY};
    float lrow[4] = {0.f, 0.f, 0.f, 0.f};

    const int qhi    = qt0 + 15;
    const int nkeys  = (qhi < 1023 ? qhi : 1023) + 1;
    const int ntiles = (nkeys + 31) >> 5;

    for (int kt = 0; kt < ntiles; ++kt) {
        const int s0 = kt << 5;
        floatx4 sA = {0,0,0,0}, sB = {0,0,0,0};
        {
            const unsigned short* kp0 = Kp + (size_t)(s0 + l15) * 64 + quad * 8;
            const unsigned short* kp1 = kp0 + 16 * 64;
            short8 k00 = lds8(kp0);
            short8 k01 = lds8(kp0 + 32);
            short8 k10 = lds8(kp1);
            short8 k11 = lds8(kp1 + 32);
            sA = MFMA16(qa0, k00, sA);
            sA = MFMA16(qa1, k01, sA);
            sB = MFMA16(qa0, k10, sB);
            sB = MFMA16(qa1, k11, sB);
        }
        float alpha[4];
#pragma unroll
        for (int r = 0; r < 4; ++r) {
            const int q = qt0 + quad * 4 + r;
            float x0 = sA[r] * 0.125f;
            float x1 = sB[r] * 0.125f;
            if (s0 + l15 > q)      x0 = -INFINITY;
            if (s0 + 16 + l15 > q) x1 = -INFINITY;
            float mt = fmaxf(x0, x1);
#pragma unroll
            for (int off = 8; off >= 1; off >>= 1) mt = fmaxf(mt, __shfl_xor(mt, off));
            const float mnew = fmaxf(mrow[r], mt);
            alpha[r] = expf(mrow[r] - mnew);
            mrow[r]  = mnew;
            float p0 = expf(x0 - mnew);
            float p1 = expf(x1 - mnew);
            float ps = p0 + p1;
#pragma unroll
            for (int off = 8; off >= 1; off >>= 1) ps += __shfl_xor(ps, off);
            lrow[r] = lrow[r] * alpha[r] + ps;
            pb[(quad * 4 + r) * 32 + l15]      = f2bf(p0);
            pb[(quad * 4 + r) * 32 + 16 + l15] = f2bf(p1);
        }
#pragma unroll
        for (int r = 0; r < 4; ++r) {
            o0[r] *= alpha[r]; o1[r] *= alpha[r]; o2[r] *= alpha[r]; o3[r] *= alpha[r];
        }
        __asm__ volatile("" ::: "memory");     // keep P writes before the A-layout read
        short8 pa = lds8(&pb[l15 * 32 + quad * 8]);
        __asm__ volatile("" ::: "memory");     // keep read before next iter's writes
        const unsigned short* vbase = Vp + s0 + quad * 8;
        o0 = MFMA16(pa, lds8(vbase + (size_t)(l15)      * 1024), o0);
        o1 = MFMA16(pa, lds8(vbase + (size_t)(16 + l15) * 1024), o1);
        o2 = MFMA16(pa, lds8(vbase + (size_t)(32 + l15) * 1024), o2);
        o3 = MFMA16(pa, lds8(vbase + (size_t)(48 + l15) * 1024), o3);
    }

    // write O[b][t][h*64+d] bf16, packed dword stores from even lanes
    unsigned short* Ob = O + (size_t)b * 4096 * 2048 + h * 64;
#pragma unroll
    for (int r = 0; r < 4; ++r) {
        const int q = qt0 + quad * 4 + r;
        const float inv = 1.f / lrow[r];
        float w0 = o0[r] * inv, w1 = o1[r] * inv, w2 = o2[r] * inv, w3 = o3[r] * inv;
        float p0 = __shfl_xor(w0, 1), p1 = __shfl_xor(w1, 1);
        float p2 = __shfl_xor(w2, 1), p3 = __shfl_xor(w3, 1);
        if (!(lane & 1)) {
            unsigned short* op = Ob + (size_t)q * 2048 + l15;
            *reinterpret_cast<unsigned int*>(op)      = (unsigned int)f2bf(w0) | ((unsigned int)f2bf(p0) << 16);
            *reinterpret_cast<unsigned int*>(op + 16) = (unsigned int)f2bf(w1) | ((unsigned int)f2bf(p1) << 16);
            *reinterpret_cast<unsigned int*>(op + 32) = (unsigned int)f2bf(w2) | ((unsigned int)f2bf(p2) << 16);
            *reinterpret_cast<unsigned int*>(op + 48) = (unsigned int)f2bf(w3) | ((unsigned int)f2bf(p3) << 16);
        }
    }
}

// ---------------- launch ----------------
extern "C" void kernel_launch(void* const* d_in, const int* in_sizes, int n_in,
                              void* d_out, int out_size, void* d_ws, size_t ws_size,
                              hipStream_t stream) {
    const float* x  = (const float*)d_in[0];
    const float* kc = (const float*)d_in[1];
    const float* vc = (const float*)d_in[2];
    const float* Wq = (const float*)d_in[3];
    const float* Wo = (const float*)d_in[4];
    float* out = (float*)d_out;

    char* ws = (char*)d_ws;
    unsigned short* Xb  = (unsigned short*)(ws);              // 33,554,432 B (reused as O)
    unsigned short* Qb  = (unsigned short*)(ws + 33554432);   // 33,554,432 B
    unsigned short* Wqb = (unsigned short*)(ws + 67108864);   //  8,388,608 B
    unsigned short* Wob = (unsigned short*)(ws + 75497472);   //  8,388,608 B
    unsigned short* Kwb = (unsigned short*)(ws + 83886080);   //  2,097,152 B
    unsigned short* Vtb = (unsigned short*)(ws + 85983232);   //  2,097,152 B

    cvt_bf16<<<16384, 256, 0, stream>>>(x,  Xb,  4194304);
    cvt_bf16<<<4096,  256, 0, stream>>>(Wq, Wqb, 1048576);
    cvt_bf16<<<4096,  256, 0, stream>>>(Wo, Wob, 1048576);
    prep_k<<<1024, 256, 0, stream>>>(kc, Kwb);
    prep_v<<<256, 256, 0, stream>>>(vc, Vtb);

    gemm_bt<0><<<1024, 256, 0, stream>>>(Xb, Wqb, nullptr, Qb);   // Q + RoPE
    attn<<<4096, 256, 0, stream>>>(Qb, Kwb, Vtb, Xb);             // O -> Xb
    gemm_bt<1><<<1024, 256, 0, stream>>>(Xb, Wob, out, nullptr);  // out proj
}

// Round 4
// 851.844 us; speedup vs baseline: 1.5110x; 1.0006x over previous
//
#include <hip/hip_runtime.h>
#include <math.h>

typedef __attribute__((ext_vector_type(8))) short short8;
typedef __attribute__((ext_vector_type(4))) float floatx4;

#define MFMA16(a, b, c) __builtin_amdgcn_mfma_f32_16x16x32_bf16((a), (b), (c), 0, 0, 0)

// log2(e) * (1/sqrt(64)) — folded into Q so attention works in exp2 domain
#define QSCALE 0.18033688011112042f

__device__ __forceinline__ unsigned short f2bf(float x) {
    unsigned int u = __float_as_uint(x);
    u += 0x7fffu + ((u >> 16) & 1u);   // round-to-nearest-even
    return (unsigned short)(u >> 16);
}

__device__ __forceinline__ short8 lds8(const unsigned short* p) {
    return *reinterpret_cast<const short8*>(p);
}

// async global->LDS, 16B per lane; LDS dest = wave-uniform base + lane*16
__device__ __forceinline__ void g2l16(const unsigned short* g, unsigned short* l) {
    __builtin_amdgcn_global_load_lds(
        (const __attribute__((address_space(1))) unsigned int*)g,
        (__attribute__((address_space(3))) unsigned int*)l,
        16, 0, 0);
}

// ---------------- prep: fp32 -> bf16 convert (vectorized) ----------------
__global__ void cvt_bf16(const float* __restrict__ src, unsigned short* __restrict__ dst, int n4) {
    int i = blockIdx.x * blockDim.x + threadIdx.x;
    if (i >= n4) return;
    float4 v = reinterpret_cast<const float4*>(src)[i];
    ushort4 o;
    o.x = f2bf(v.x); o.y = f2bf(v.y); o.z = f2bf(v.z); o.w = f2bf(v.w);
    reinterpret_cast<ushort4*>(dst)[i] = o;
}

// ---------------- prep: K window convert (coalesced both sides) ----------------
__global__ void prep_k(const float* __restrict__ kc, unsigned short* __restrict__ Kw) {
    int i = blockIdx.x * blockDim.x + threadIdx.x;   // 0 .. 262143
    int d4  = (i & 15) * 4;
    int s   = (i >> 4) & 1023;
    int bkv = i >> 14;
    size_t src = ((size_t)bkv * 4096 + 3072 + s) * 64 + d4;
    float4 kv = *reinterpret_cast<const float4*>(kc + src);
    ushort4 ko;
    ko.x = f2bf(kv.x); ko.y = f2bf(kv.y); ko.z = f2bf(kv.z); ko.w = f2bf(kv.w);
    *reinterpret_cast<ushort4*>(Kw + ((size_t)bkv * 1024 + s) * 64 + d4) = ko;
}

// ---------------- prep: V window transpose via LDS tile ----------------
__global__ void prep_v(const float* __restrict__ vc, unsigned short* __restrict__ Vt) {
    __shared__ unsigned short tl[64][72];
    const int bkv = blockIdx.x >> 4;
    const int s0  = (blockIdx.x & 15) * 64;
    const int t   = threadIdx.x;
    const int sl  = t >> 2;
    const int dq  = (t & 3) * 16;
    const float* src = vc + ((size_t)bkv * 4096 + 3072 + s0 + sl) * 64 + dq;
    float4 v0 = reinterpret_cast<const float4*>(src)[0];
    float4 v1 = reinterpret_cast<const float4*>(src)[1];
    float4 v2 = reinterpret_cast<const float4*>(src)[2];
    float4 v3 = reinterpret_cast<const float4*>(src)[3];
    tl[dq +  0][sl] = f2bf(v0.x); tl[dq +  1][sl] = f2bf(v0.y);
    tl[dq +  2][sl] = f2bf(v0.z); tl[dq +  3][sl] = f2bf(v0.w);
    tl[dq +  4][sl] = f2bf(v1.x); tl[dq +  5][sl] = f2bf(v1.y);
    tl[dq +  6][sl] = f2bf(v1.z); tl[dq +  7][sl] = f2bf(v1.w);
    tl[dq +  8][sl] = f2bf(v2.x); tl[dq +  9][sl] = f2bf(v2.y);
    tl[dq + 10][sl] = f2bf(v2.z); tl[dq + 11][sl] = f2bf(v2.w);
    tl[dq + 12][sl] = f2bf(v3.x); tl[dq + 13][sl] = f2bf(v3.y);
    tl[dq + 14][sl] = f2bf(v3.z); tl[dq + 15][sl] = f2bf(v3.w);
    __syncthreads();
    const int dl = t >> 2;
    const int sc = (t & 3) * 16;
    unsigned short* dst = Vt + ((size_t)bkv * 64 + dl) * 1024 + s0 + sc;
    short8 x0 = *reinterpret_cast<const short8*>(&tl[dl][sc]);
    short8 x1 = *reinterpret_cast<const short8*>(&tl[dl][sc + 8]);
    *reinterpret_cast<short8*>(dst)     = x0;
    *reinterpret_cast<short8*>(dst + 8) = x1;
}

// ---------------- bf16 MFMA GEMM (m97 structure): C = A[M,K] * Bt[N,K]^T ----------------
template <int EPI>
__global__ __launch_bounds__(256)
void gemm_bt(const unsigned short* __restrict__ A,
             const unsigned short* __restrict__ Bt,
             float* __restrict__ Cf,
             unsigned short* __restrict__ Cb) {
    constexpr int K = 2048;
    __shared__ unsigned short As[128 * 32];
    __shared__ unsigned short Bs[128 * 32];

    const int tid  = threadIdx.x;
    const int lane = tid & 63;
    const int l15  = lane & 15;
    const int quad = lane >> 4;
    const int wid  = tid >> 6;
    const int wm   = (wid & 1) * 64;
    const int wn   = (wid >> 1) * 64;

    const int bn = blockIdx.x & 15;
    const int bm = blockIdx.x >> 4;

    const int row0 = tid >> 2;
    const int kc8  = (tid & 3) * 8;
    const unsigned short* Ag0 = A  + (size_t)(bm * 128 + row0) * K + kc8;
    const unsigned short* Ag1 = Ag0 + (size_t)64 * K;
    const unsigned short* Bg0 = Bt + (size_t)(bn * 128 + row0) * K + kc8;
    const unsigned short* Bg1 = Bg0 + (size_t)64 * K;
    unsigned short* AsW0 = As + wid * 512;
    unsigned short* AsW1 = As + 2048 + wid * 512;
    unsigned short* BsW0 = Bs + wid * 512;
    unsigned short* BsW1 = Bs + 2048 + wid * 512;

    floatx4 c00 = {0,0,0,0}, c01 = {0,0,0,0}, c02 = {0,0,0,0}, c03 = {0,0,0,0};
    floatx4 c10 = {0,0,0,0}, c11 = {0,0,0,0}, c12 = {0,0,0,0}, c13 = {0,0,0,0};
    floatx4 c20 = {0,0,0,0}, c21 = {0,0,0,0}, c22 = {0,0,0,0}, c23 = {0,0,0,0};
    floatx4 c30 = {0,0,0,0}, c31 = {0,0,0,0}, c32 = {0,0,0,0}, c33 = {0,0,0,0};

    for (int k0 = 0; k0 < K; k0 += 32) {
        __syncthreads();
        g2l16(Ag0 + k0, AsW0);
        g2l16(Ag1 + k0, AsW1);
        g2l16(Bg0 + k0, BsW0);
        g2l16(Bg1 + k0, BsW1);
        __syncthreads();

        short8 a0 = lds8(&As[(wm +  0 + l15) * 32 + quad * 8]);
        short8 a1 = lds8(&As[(wm + 16 + l15) * 32 + quad * 8]);
        short8 a2 = lds8(&As[(wm + 32 + l15) * 32 + quad * 8]);
        short8 a3 = lds8(&As[(wm + 48 + l15) * 32 + quad * 8]);
        short8 b0 = lds8(&Bs[(wn +  0 + l15) * 32 + quad * 8]);
        short8 b1 = lds8(&Bs[(wn + 16 + l15) * 32 + quad * 8]);
        short8 b2 = lds8(&Bs[(wn + 32 + l15) * 32 + quad * 8]);
        short8 b3 = lds8(&Bs[(wn + 48 + l15) * 32 + quad * 8]);

        c00 = MFMA16(a0, b0, c00); c01 = MFMA16(a0, b1, c01);
        c02 = MFMA16(a0, b2, c02); c03 = MFMA16(a0, b3, c03);
        c10 = MFMA16(a1, b0, c10); c11 = MFMA16(a1, b1, c11);
        c12 = MFMA16(a1, b2, c12); c13 = MFMA16(a1, b3, c13);
        c20 = MFMA16(a2, b0, c20); c21 = MFMA16(a2, b1, c21);
        c22 = MFMA16(a2, b2, c22); c23 = MFMA16(a2, b3, c23);
        c30 = MFMA16(a3, b0, c30); c31 = MFMA16(a3, b1, c31);
        c32 = MFMA16(a3, b2, c32); c33 = MFMA16(a3, b3, c33);
    }

#define EPI_TILE(i, j, C) do {                                                  \
    _Pragma("unroll")                                                           \
    for (int r = 0; r < 4; ++r) {                                               \
        int row = bm * 128 + wm + (i) * 16 + quad * 4 + r;                      \
        int col = bn * 128 + wn + (j) * 16 + l15;                               \
        float v = (C)[r];                                                       \
        if (EPI == 0) {                                                         \
            float p = __shfl_xor(v, 1);                                         \
            int t = row & 4095, b = row >> 12;                                  \
            int hh = col >> 6, d = col & 63;                                    \
            float f = (float)t * exp2f(-(float)(d >> 1) * 0.41524101186092f);   \
            float sn, cs; sincosf(f, &sn, &cs);                                 \
            float o = (d & 1) ? (p * sn + v * cs) : (v * cs - p * sn);          \
            o *= QSCALE;                                                        \
            float po = __shfl_xor(o, 1);                                        \
            if (!(lane & 1)) {                                                  \
                unsigned int pk = (unsigned int)f2bf(o) |                       \
                                  ((unsigned int)f2bf(po) << 16);               \
                *reinterpret_cast<unsigned int*>(                               \
                    Cb + ((size_t)((b * 32 + hh) * 4096 + t)) * 64 + d) = pk;   \
            }                                                                   \
        } else {                                                                \
            Cf[(size_t)row * 2048 + col] = v;                                   \
        }                                                                       \
    }                                                                           \
} while (0)

    EPI_TILE(0, 0, c00); EPI_TILE(0, 1, c01); EPI_TILE(0, 2, c02); EPI_TILE(0, 3, c03);
    EPI_TILE(1, 0, c10); EPI_TILE(1, 1, c11); EPI_TILE(1, 2, c12); EPI_TILE(1, 3, c13);
    EPI_TILE(2, 0, c20); EPI_TILE(2, 1, c21); EPI_TILE(2, 2, c22); EPI_TILE(2, 3, c23);
    EPI_TILE(3, 0, c30); EPI_TILE(3, 1, c31); EPI_TILE(3, 2, c32); EPI_TILE(3, 3, c33);
#undef EPI_TILE
}

// ---------------- flash attention over 1024-key window ----------------
// 64-key tiles, wave-shared online max (exp2 domain; scale folded into Q),
// per-lane partial l (one final ladder), mask only in the single last tile.
// Key range CLAMPED to the 1024-key window (R3 bug: clamp was dropped).
__global__ __launch_bounds__(256)
void attn(const unsigned short* __restrict__ Q,
          const unsigned short* __restrict__ Kw,
          const unsigned short* __restrict__ Vt,
          unsigned short* __restrict__ O) {
    const int blk   = blockIdx.x;
    const int qtile = blk & 63;
    const int bh    = blk >> 6;
    const int h     = bh & 31;
    const int b     = bh >> 5;
    const int kvh   = h >> 2;

    const int tid  = threadIdx.x;
    const int lane = tid & 63;
    const int l15  = lane & 15;
    const int quad = lane >> 4;
    const int wid  = tid >> 6;
    const int qt0  = qtile * 64 + wid * 16;

    const unsigned short* Qp = Q  + ((size_t)bh * 4096 + qt0) * 64;
    const unsigned short* Kp = Kw + (size_t)(b * 8 + kvh) * 1024 * 64;
    const unsigned short* Vp = Vt + (size_t)(b * 8 + kvh) * 64 * 1024;

    __shared__ unsigned short Pbuf[4][16 * 72];   // pitch 72: +16B pad per row
    unsigned short* pb = Pbuf[wid];

    short8 qa0 = lds8(&Qp[l15 * 64 + quad * 8]);
    short8 qa1 = lds8(&Qp[l15 * 64 + 32 + quad * 8]);

    floatx4 o0 = {0,0,0,0}, o1 = {0,0,0,0}, o2 = {0,0,0,0}, o3 = {0,0,0,0};
    float L[4] = {0.f, 0.f, 0.f, 0.f};
    float m = -INFINITY;
    floatx4 sS[4];

    const int qhi   = qt0 + 15;
    const int nkeys = (qhi < 1023 ? qhi : 1023) + 1;   // clamp to window!
    const int n64   = (nkeys + 63) >> 6;
    const int nfull = n64 - 1;

    // softmax + PV for one 64-key tile; sS already masked if needed
    auto process = [&](int s0, bool skipHi) {
        float mx = sS[0][0];
#pragma unroll
        for (int c = 0; c < 4; ++c)
#pragma unroll
            for (int r = 0; r < 4; ++r) mx = fmaxf(mx, sS[c][r]);
#pragma unroll
        for (int off = 32; off >= 1; off >>= 1) mx = fmaxf(mx, __shfl_xor(mx, off));
        const float mnew  = fmaxf(m, mx);
        const float alpha = exp2f(m - mnew);
        m = mnew;

        float p[4][4];
#pragma unroll
        for (int c = 0; c < 4; ++c)
#pragma unroll
            for (int r = 0; r < 4; ++r) p[c][r] = exp2f(sS[c][r] - mnew);

#pragma unroll
        for (int r = 0; r < 4; ++r)
            L[r] = L[r] * alpha + ((p[0][r] + p[1][r]) + (p[2][r] + p[3][r]));
#pragma unroll
        for (int r = 0; r < 4; ++r) {
            o0[r] *= alpha; o1[r] *= alpha; o2[r] *= alpha; o3[r] *= alpha;
        }

        const bool ev = !(l15 & 1);
        const int  col0 = ev ? l15 : 31 + l15;
#pragma unroll
        for (int r = 0; r < 4; ++r) {
            const int row = quad * 4 + r;
            unsigned int ru0 = __float_as_uint(p[0][r]) + 0x8000u;
            unsigned int ru1 = __float_as_uint(p[1][r]) + 0x8000u;
            unsigned int ru2 = __float_as_uint(p[2][r]) + 0x8000u;
            unsigned int ru3 = __float_as_uint(p[3][r]) + 0x8000u;
            unsigned int qu0 = (unsigned int)__shfl_xor((int)ru0, 1);
            unsigned int qu1 = (unsigned int)__shfl_xor((int)ru1, 1);
            unsigned int qu2 = (unsigned int)__shfl_xor((int)ru2, 1);
            unsigned int qu3 = (unsigned int)__shfl_xor((int)ru3, 1);
            unsigned int lo0 = ev ? ru0 : qu2, hi0 = ev ? qu0 : ru2;
            unsigned int lo1 = ev ? ru1 : qu3, hi1 = ev ? qu1 : ru3;
            unsigned int w0 = __builtin_amdgcn_perm(hi0, lo0, 0x07060302u);
            unsigned int w1 = __builtin_amdgcn_perm(hi1, lo1, 0x07060302u);
            *reinterpret_cast<unsigned int*>(&pb[row * 72 + col0])      = w0;
            *reinterpret_cast<unsigned int*>(&pb[row * 72 + col0 + 16]) = w1;
        }
        __asm__ volatile("" ::: "memory");
        short8 pa = lds8(&pb[l15 * 72 + quad * 8]);
        const unsigned short* vb = Vp + s0 + quad * 8;
        o0 = MFMA16(pa, lds8(vb + (size_t)(l15)      * 1024), o0);
        o1 = MFMA16(pa, lds8(vb + (size_t)(16 + l15) * 1024), o1);
        o2 = MFMA16(pa, lds8(vb + (size_t)(32 + l15) * 1024), o2);
        o3 = MFMA16(pa, lds8(vb + (size_t)(48 + l15) * 1024), o3);
        if (!skipHi) {
            short8 pa2 = lds8(&pb[l15 * 72 + 32 + quad * 8]);
            const unsigned short* vb2 = vb + 32;
            o0 = MFMA16(pa2, lds8(vb2 + (size_t)(l15)      * 1024), o0);
            o1 = MFMA16(pa2, lds8(vb2 + (size_t)(16 + l15) * 1024), o1);
            o2 = MFMA16(pa2, lds8(vb2 + (size_t)(32 + l15) * 1024), o2);
            o3 = MFMA16(pa2, lds8(vb2 + (size_t)(48 + l15) * 1024), o3);
        }
        __asm__ volatile("" ::: "memory");
    };

    // full (unmasked) tiles
    for (int it = 0; it < nfull; ++it) {
        const int s0 = it << 6;
#pragma unroll
        for (int c = 0; c < 4; ++c) {
            const unsigned short* kp = Kp + (size_t)(s0 + c * 16 + l15) * 64 + quad * 8;
            floatx4 z = {0, 0, 0, 0};
            z = MFMA16(qa0, lds8(kp), z);
            z = MFMA16(qa1, lds8(kp + 32), z);
            sS[c] = z;
        }
        process(s0, false);
    }

    // last tile (masked iff the query is within the first window span)
    {
        const int s0 = nfull << 6;
        const int nchunk = (nkeys - s0 + 15) >> 4;   // 1..4, wave-uniform
#pragma unroll
        for (int c = 0; c < 4; ++c) {
            floatx4 z = {0, 0, 0, 0};
            if (c < nchunk) {
                const unsigned short* kp = Kp + (size_t)(s0 + c * 16 + l15) * 64 + quad * 8;
                z = MFMA16(qa0, lds8(kp), z);
                z = MFMA16(qa1, lds8(kp + 32), z);
            }
            sS[c] = z;
        }
#pragma unroll
        for (int c = 0; c < 4; ++c)
#pragma unroll
            for (int r = 0; r < 4; ++r)
                if (s0 + c * 16 + l15 > qt0 + quad * 4 + r) sS[c][r] = -INFINITY;
        process(s0, nchunk <= 2);
    }

    // final per-row l reduction (keys live on l15 lanes)
#pragma unroll
    for (int r = 0; r < 4; ++r) {
        float l = L[r];
#pragma unroll
        for (int off = 8; off >= 1; off >>= 1) l += __shfl_xor(l, off);
        L[r] = l;
    }

    // write O[b][t][h*64+d] bf16, packed dword stores from even lanes
    unsigned short* Ob = O + (size_t)b * 4096 * 2048 + h * 64;
#pragma unroll
    for (int r = 0; r < 4; ++r) {
        const int q = qt0 + quad * 4 + r;
        const float inv = 1.f / L[r];
        float w0 = o0[r] * inv, w1 = o1[r] * inv, w2 = o2[r] * inv, w3 = o3[r] * inv;
        float p0 = __shfl_xor(w0, 1), p1 = __shfl_xor(w1, 1);
        float p2 = __shfl_xor(w2, 1), p3 = __shfl_xor(w3, 1);
        if (!(lane & 1)) {
            unsigned short* op = Ob + (size_t)q * 2048 + l15;
            *reinterpret_cast<unsigned int*>(op)      = (unsigned int)f2bf(w0) | ((unsigned int)f2bf(p0) << 16);
            *reinterpret_cast<unsigned int*>(op + 16) = (unsigned int)f2bf(w1) | ((unsigned int)f2bf(p1) << 16);
            *reinterpret_cast<unsigned int*>(op + 32) = (unsigned int)f2bf(w2) | ((unsigned int)f2bf(p2) << 16);
            *reinterpret_cast<unsigned int*>(op + 48) = (unsigned int)f2bf(w3) | ((unsigned int)f2bf(p3) << 16);
        }
    }
}

// ---------------- launch ----------------
extern "C" void kernel_launch(void* const* d_in, const int* in_sizes, int n_in,
                              void* d_out, int out_size, void* d_ws, size_t ws_size,
                              hipStream_t stream) {
    const float* x  = (const float*)d_in[0];
    const float* kc = (const float*)d_in[1];
    const float* vc = (const float*)d_in[2];
    const float* Wq = (const float*)d_in[3];
    const float* Wo = (const float*)d_in[4];
    float* out = (float*)d_out;

    char* ws = (char*)d_ws;
    unsigned short* Xb  = (unsigned short*)(ws);              // 33,554,432 B (reused as O)
    unsigned short* Qb  = (unsigned short*)(ws + 33554432);   // 33,554,432 B
    unsigned short* Wqb = (unsigned short*)(ws + 67108864);   //  8,388,608 B
    unsigned short* Wob = (unsigned short*)(ws + 75497472);   //  8,388,608 B
    unsigned short* Kwb = (unsigned short*)(ws + 83886080);   //  2,097,152 B
    unsigned short* Vtb = (unsigned short*)(ws + 85983232);   //  2,097,152 B

    cvt_bf16<<<16384, 256, 0, stream>>>(x,  Xb,  4194304);
    cvt_bf16<<<4096,  256, 0, stream>>>(Wq, Wqb, 1048576);
    cvt_bf16<<<4096,  256, 0, stream>>>(Wo, Wob, 1048576);
    prep_k<<<1024, 256, 0, stream>>>(kc, Kwb);
    prep_v<<<256, 256, 0, stream>>>(vc, Vtb);

    gemm_bt<0><<<1024, 256, 0, stream>>>(Xb, Wqb, nullptr, Qb);   // Q + RoPE (pre-scaled)
    attn<<<4096, 256, 0, stream>>>(Qb, Kwb, Vtb, Xb);             // O -> Xb
    gemm_bt<1><<<1024, 256, 0, stream>>>(Xb, Wob, out, nullptr);  // out proj
}

// Round 5
// 565.834 us; speedup vs baseline: 2.2747x; 1.5055x over previous
//
#include <hip/hip_runtime.h>
#include <math.h>

typedef __attribute__((ext_vector_type(8))) short short8;
typedef __attribute__((ext_vector_type(4))) float floatx4;

#define MFMA16(a, b, c) __builtin_amdgcn_mfma_f32_16x16x32_bf16((a), (b), (c), 0, 0, 0)

// log2(e) * (1/sqrt(64)) — folded into Q so attention works in exp2 domain
#define QSCALE 0.18033688011112042f

__device__ __forceinline__ unsigned short f2bf(float x) {
    unsigned int u = __float_as_uint(x);
    u += 0x7fffu + ((u >> 16) & 1u);   // round-to-nearest-even
    return (unsigned short)(u >> 16);
}

__device__ __forceinline__ short8 lds8(const unsigned short* p) {
    return *reinterpret_cast<const short8*>(p);
}

// async global->LDS, 16B per lane; LDS dest = wave-uniform base + lane*16
__device__ __forceinline__ void g2l16(const unsigned short* g, unsigned short* l) {
    __builtin_amdgcn_global_load_lds(
        (const __attribute__((address_space(1))) unsigned int*)g,
        (__attribute__((address_space(3))) unsigned int*)l,
        16, 0, 0);
}

// ---------------- prep: fp32 -> bf16 convert (vectorized) ----------------
__global__ void cvt_bf16(const float* __restrict__ src, unsigned short* __restrict__ dst, int n4) {
    int i = blockIdx.x * blockDim.x + threadIdx.x;
    if (i >= n4) return;
    float4 v = reinterpret_cast<const float4*>(src)[i];
    ushort4 o;
    o.x = f2bf(v.x); o.y = f2bf(v.y); o.z = f2bf(v.z); o.w = f2bf(v.w);
    reinterpret_cast<ushort4*>(dst)[i] = o;
}

// ---------------- prep: K window convert (coalesced both sides) ----------------
__global__ void prep_k(const float* __restrict__ kc, unsigned short* __restrict__ Kw) {
    int i = blockIdx.x * blockDim.x + threadIdx.x;   // 0 .. 262143
    int d4  = (i & 15) * 4;
    int s   = (i >> 4) & 1023;
    int bkv = i >> 14;
    size_t src = ((size_t)bkv * 4096 + 3072 + s) * 64 + d4;
    float4 kv = *reinterpret_cast<const float4*>(kc + src);
    ushort4 ko;
    ko.x = f2bf(kv.x); ko.y = f2bf(kv.y); ko.z = f2bf(kv.z); ko.w = f2bf(kv.w);
    *reinterpret_cast<ushort4*>(Kw + ((size_t)bkv * 1024 + s) * 64 + d4) = ko;
}

// ---------------- prep: V window transpose via LDS tile ----------------
__global__ void prep_v(const float* __restrict__ vc, unsigned short* __restrict__ Vt) {
    __shared__ unsigned short tl[64][72];
    const int bkv = blockIdx.x >> 4;
    const int s0  = (blockIdx.x & 15) * 64;
    const int t   = threadIdx.x;
    const int sl  = t >> 2;
    const int dq  = (t & 3) * 16;
    const float* src = vc + ((size_t)bkv * 4096 + 3072 + s0 + sl) * 64 + dq;
    float4 v0 = reinterpret_cast<const float4*>(src)[0];
    float4 v1 = reinterpret_cast<const float4*>(src)[1];
    float4 v2 = reinterpret_cast<const float4*>(src)[2];
    float4 v3 = reinterpret_cast<const float4*>(src)[3];
    tl[dq +  0][sl] = f2bf(v0.x); tl[dq +  1][sl] = f2bf(v0.y);
    tl[dq +  2][sl] = f2bf(v0.z); tl[dq +  3][sl] = f2bf(v0.w);
    tl[dq +  4][sl] = f2bf(v1.x); tl[dq +  5][sl] = f2bf(v1.y);
    tl[dq +  6][sl] = f2bf(v1.z); tl[dq +  7][sl] = f2bf(v1.w);
    tl[dq +  8][sl] = f2bf(v2.x); tl[dq +  9][sl] = f2bf(v2.y);
    tl[dq + 10][sl] = f2bf(v2.z); tl[dq + 11][sl] = f2bf(v2.w);
    tl[dq + 12][sl] = f2bf(v3.x); tl[dq + 13][sl] = f2bf(v3.y);
    tl[dq + 14][sl] = f2bf(v3.z); tl[dq + 15][sl] = f2bf(v3.w);
    __syncthreads();
    const int dl = t >> 2;
    const int sc = (t & 3) * 16;
    unsigned short* dst = Vt + ((size_t)bkv * 64 + dl) * 1024 + s0 + sc;
    short8 x0 = *reinterpret_cast<const short8*>(&tl[dl][sc]);
    short8 x1 = *reinterpret_cast<const short8*>(&tl[dl][sc + 8]);
    *reinterpret_cast<short8*>(dst)     = x0;
    *reinterpret_cast<short8*>(dst + 8) = x1;
}

// ---------------- bf16 MFMA GEMM (m97 structure): C = A[M,K] * Bt[N,K]^T ----------------
template <int EPI>
__global__ __launch_bounds__(256)
void gemm_bt(const unsigned short* __restrict__ A,
             const unsigned short* __restrict__ Bt,
             float* __restrict__ Cf,
             unsigned short* __restrict__ Cb) {
    constexpr int K = 2048;
    __shared__ unsigned short As[128 * 32];
    __shared__ unsigned short Bs[128 * 32];

    const int tid  = threadIdx.x;
    const int lane = tid & 63;
    const int l15  = lane & 15;
    const int quad = lane >> 4;
    const int wid  = tid >> 6;
    const int wm   = (wid & 1) * 64;
    const int wn   = (wid >> 1) * 64;

    const int bn = blockIdx.x & 15;
    const int bm = blockIdx.x >> 4;

    const int row0 = tid >> 2;
    const int kc8  = (tid & 3) * 8;
    const unsigned short* Ag0 = A  + (size_t)(bm * 128 + row0) * K + kc8;
    const unsigned short* Ag1 = Ag0 + (size_t)64 * K;
    const unsigned short* Bg0 = Bt + (size_t)(bn * 128 + row0) * K + kc8;
    const unsigned short* Bg1 = Bg0 + (size_t)64 * K;
    unsigned short* AsW0 = As + wid * 512;
    unsigned short* AsW1 = As + 2048 + wid * 512;
    unsigned short* BsW0 = Bs + wid * 512;
    unsigned short* BsW1 = Bs + 2048 + wid * 512;

    floatx4 c00 = {0,0,0,0}, c01 = {0,0,0,0}, c02 = {0,0,0,0}, c03 = {0,0,0,0};
    floatx4 c10 = {0,0,0,0}, c11 = {0,0,0,0}, c12 = {0,0,0,0}, c13 = {0,0,0,0};
    floatx4 c20 = {0,0,0,0}, c21 = {0,0,0,0}, c22 = {0,0,0,0}, c23 = {0,0,0,0};
    floatx4 c30 = {0,0,0,0}, c31 = {0,0,0,0}, c32 = {0,0,0,0}, c33 = {0,0,0,0};

    for (int k0 = 0; k0 < K; k0 += 32) {
        __syncthreads();
        g2l16(Ag0 + k0, AsW0);
        g2l16(Ag1 + k0, AsW1);
        g2l16(Bg0 + k0, BsW0);
        g2l16(Bg1 + k0, BsW1);
        __syncthreads();

        short8 a0 = lds8(&As[(wm +  0 + l15) * 32 + quad * 8]);
        short8 a1 = lds8(&As[(wm + 16 + l15) * 32 + quad * 8]);
        short8 a2 = lds8(&As[(wm + 32 + l15) * 32 + quad * 8]);
        short8 a3 = lds8(&As[(wm + 48 + l15) * 32 + quad * 8]);
        short8 b0 = lds8(&Bs[(wn +  0 + l15) * 32 + quad * 8]);
        short8 b1 = lds8(&Bs[(wn + 16 + l15) * 32 + quad * 8]);
        short8 b2 = lds8(&Bs[(wn + 32 + l15) * 32 + quad * 8]);
        short8 b3 = lds8(&Bs[(wn + 48 + l15) * 32 + quad * 8]);

        c00 = MFMA16(a0, b0, c00); c01 = MFMA16(a0, b1, c01);
        c02 = MFMA16(a0, b2, c02); c03 = MFMA16(a0, b3, c03);
        c10 = MFMA16(a1, b0, c10); c11 = MFMA16(a1, b1, c11);
        c12 = MFMA16(a1, b2, c12); c13 = MFMA16(a1, b3, c13);
        c20 = MFMA16(a2, b0, c20); c21 = MFMA16(a2, b1, c21);
        c22 = MFMA16(a2, b2, c22); c23 = MFMA16(a2, b3, c23);
        c30 = MFMA16(a3, b0, c30); c31 = MFMA16(a3, b1, c31);
        c32 = MFMA16(a3, b2, c32); c33 = MFMA16(a3, b3, c33);
    }

#define EPI_TILE(i, j, C) do {                                                  \
    _Pragma("unroll")                                                           \
    for (int r = 0; r < 4; ++r) {                                               \
        int row = bm * 128 + wm + (i) * 16 + quad * 4 + r;                      \
        int col = bn * 128 + wn + (j) * 16 + l15;                               \
        float v = (C)[r];                                                       \
        if (EPI == 0) {                                                         \
            float p = __shfl_xor(v, 1);                                         \
            int t = row & 4095, b = row >> 12;                                  \
            int hh = col >> 6, d = col & 63;                                    \
            float f = (float)t * exp2f(-(float)(d >> 1) * 0.41524101186092f);   \
            float sn, cs; __sincosf(f, &sn, &cs);                               \
            float o = (d & 1) ? (p * sn + v * cs) : (v * cs - p * sn);          \
            o *= QSCALE;                                                        \
            float po = __shfl_xor(o, 1);                                        \
            if (!(lane & 1)) {                                                  \
                unsigned int pk = (unsigned int)f2bf(o) |                       \
                                  ((unsigned int)f2bf(po) << 16);               \
                *reinterpret_cast<unsigned int*>(                               \
                    Cb + ((size_t)((b * 32 + hh) * 4096 + t)) * 64 + d) = pk;   \
            }                                                                   \
        } else {                                                                \
            Cf[(size_t)row * 2048 + col] = v;                                   \
        }                                                                       \
    }                                                                           \
} while (0)

    EPI_TILE(0, 0, c00); EPI_TILE(0, 1, c01); EPI_TILE(0, 2, c02); EPI_TILE(0, 3, c03);
    EPI_TILE(1, 0, c10); EPI_TILE(1, 1, c11); EPI_TILE(1, 2, c12); EPI_TILE(1, 3, c13);
    EPI_TILE(2, 0, c20); EPI_TILE(2, 1, c21); EPI_TILE(2, 2, c22); EPI_TILE(2, 3, c23);
    EPI_TILE(3, 0, c30); EPI_TILE(3, 1, c31); EPI_TILE(3, 2, c32); EPI_TILE(3, 3, c33);
#undef EPI_TILE
}

// ---------------- flash attention over 1024-key window ----------------
// Block = (bh, 64 queries), 4 waves of 16 queries. K/V tiles (64 keys) staged
// in LDS ONCE PER BLOCK via global_load_lds, double-buffered (prefetch next
// tile during compute). LDS layout = exact MFMA fragment order (lane*16B) so
// ds_read_b128 fragment reads are conflict-free. Mask only in diagonal tile.
__global__ __launch_bounds__(256)
void attn(const unsigned short* __restrict__ Q,
          const unsigned short* __restrict__ Kw,
          const unsigned short* __restrict__ Vt,
          unsigned short* __restrict__ O) {
    const int blk   = blockIdx.x;
    const int qtile = blk & 63;
    const int bh    = blk >> 6;
    const int h     = bh & 31;
    const int b     = bh >> 5;
    const int kvh   = h >> 2;

    const int tid  = threadIdx.x;
    const int lane = tid & 63;
    const int l15  = lane & 15;
    const int quad = lane >> 4;
    const int wid  = tid >> 6;
    const int qt0  = qtile * 64 + wid * 16;

    const unsigned short* Qp = Q  + ((size_t)bh * 4096 + qt0) * 64;
    const unsigned short* Kp = Kw + (size_t)(b * 8 + kvh) * 1024 * 64;
    const unsigned short* Vp = Vt + (size_t)(b * 8 + kvh) * 64 * 1024;

    // [buf][frag(8) * 512 + lane*8]; frag (c*2+half) for K, (j*2+shalf) for V
    __shared__ unsigned short Ks[2][4096];
    __shared__ unsigned short Vs[2][4096];
    __shared__ unsigned short Pbuf[4][16 * 72];   // per-wave, row pitch 72
    unsigned short* pb = Pbuf[wid];

    short8 qa0 = lds8(&Qp[l15 * 64 + quad * 8]);
    short8 qa1 = lds8(&Qp[l15 * 64 + 32 + quad * 8]);

    // staging source addrs: wave w stages K frag c=w (both halves), V frag j=w
    const unsigned short* gK = Kp + (size_t)(wid * 16 + l15) * 64 + quad * 8;
    const unsigned short* gV = Vp + (size_t)(wid * 16 + l15) * 1024 + quad * 8;

    const int ntiles = (qtile < 15 ? qtile + 1 : 16);       // block-uniform
    const int nkW    = (qt0 + 16 < 1024) ? qt0 + 16 : 1024; // per-wave keys
    const bool diag  = (qtile < 16);

    // prefetch tile 0
    g2l16(gK,      &Ks[0][wid * 1024]);
    g2l16(gK + 32, &Ks[0][wid * 1024 + 512]);
    g2l16(gV,      &Vs[0][wid * 1024]);
    g2l16(gV + 32, &Vs[0][wid * 1024 + 512]);

    floatx4 o0 = {0,0,0,0}, o1 = {0,0,0,0}, o2 = {0,0,0,0}, o3 = {0,0,0,0};
    float L[4] = {0.f, 0.f, 0.f, 0.f};
    float m = -INFINITY;

    for (int it = 0; it < ntiles; ++it) {
        __syncthreads();                         // staging of tile `it` complete
        const int cur = it & 1;
        if (it + 1 < ntiles) {                   // prefetch next into other buffer
            const int nxt = cur ^ 1;
            const unsigned short* gKn = gK + (it + 1) * 4096;
            const unsigned short* gVn = gV + (it + 1) * 64;
            g2l16(gKn,      &Ks[nxt][wid * 1024]);
            g2l16(gKn + 32, &Ks[nxt][wid * 1024 + 512]);
            g2l16(gVn,      &Vs[nxt][wid * 1024]);
            g2l16(gVn + 32, &Vs[nxt][wid * 1024 + 512]);
        }
        const int s0 = it << 6;
        const unsigned short* Kc = Ks[cur];
        const unsigned short* Vc = Vs[cur];

        // QK^T: 4 chunks of 16 keys
        floatx4 sS[4];
#pragma unroll
        for (int c = 0; c < 4; ++c) {
            floatx4 z = {0, 0, 0, 0};
            z = MFMA16(qa0, lds8(Kc + c * 1024 + lane * 8), z);
            z = MFMA16(qa1, lds8(Kc + c * 1024 + 512 + lane * 8), z);
            sS[c] = z;
        }

        const bool last = (it == ntiles - 1);
        bool skipHi = false;
        if (last && diag) {                      // diagonal tile: causal mask
#pragma unroll
            for (int c = 0; c < 4; ++c)
#pragma unroll
                for (int r = 0; r < 4; ++r)
                    if (s0 + c * 16 + l15 > qt0 + quad * 4 + r) sS[c][r] = -INFINITY;
            skipHi = (nkW - s0 <= 32);
        }

        // online softmax (exp2 domain)
        float mx = sS[0][0];
#pragma unroll
        for (int c = 0; c < 4; ++c)
#pragma unroll
            for (int r = 0; r < 4; ++r) mx = fmaxf(mx, sS[c][r]);
#pragma unroll
        for (int off = 32; off >= 1; off >>= 1) mx = fmaxf(mx, __shfl_xor(mx, off));
        if (mx > m) {                            // wave-uniform rescale (rare after warmup)
            const float alpha = exp2f(m - mx);
            m = mx;
#pragma unroll
            for (int r = 0; r < 4; ++r) {
                o0[r] *= alpha; o1[r] *= alpha; o2[r] *= alpha; o3[r] *= alpha;
                L[r] *= alpha;
            }
        }
        float p[4][4];
#pragma unroll
        for (int c = 0; c < 4; ++c)
#pragma unroll
            for (int r = 0; r < 4; ++r) p[c][r] = exp2f(sS[c][r] - m);
#pragma unroll
        for (int r = 0; r < 4; ++r)
            L[r] += (p[0][r] + p[1][r]) + (p[2][r] + p[3][r]);

        // pack P (truncating) into per-wave LDS, C-layout -> A-layout
        const bool evn = !(l15 & 1);
        const int  col0 = evn ? l15 : 31 + l15;
#pragma unroll
        for (int r = 0; r < 4; ++r) {
            const int row = quad * 4 + r;
            unsigned int u0 = __float_as_uint(p[0][r]);
            unsigned int u1 = __float_as_uint(p[1][r]);
            unsigned int u2 = __float_as_uint(p[2][r]);
            unsigned int u3 = __float_as_uint(p[3][r]);
            unsigned int q0 = (unsigned int)__shfl_xor((int)u0, 1);
            unsigned int q1 = (unsigned int)__shfl_xor((int)u1, 1);
            unsigned int q2 = (unsigned int)__shfl_xor((int)u2, 1);
            unsigned int q3 = (unsigned int)__shfl_xor((int)u3, 1);
            unsigned int lo0 = evn ? u0 : q2, hi0 = evn ? q0 : u2;
            unsigned int lo1 = evn ? u1 : q3, hi1 = evn ? q1 : u3;
            unsigned int w0 = __builtin_amdgcn_perm(hi0, lo0, 0x07060302u);
            unsigned int w1 = __builtin_amdgcn_perm(hi1, lo1, 0x07060302u);
            *reinterpret_cast<unsigned int*>(&pb[row * 72 + col0])      = w0;
            *reinterpret_cast<unsigned int*>(&pb[row * 72 + col0 + 16]) = w1;
        }
        __asm__ volatile("" ::: "memory");       // P writes before A-layout read

        short8 pa_lo = lds8(&pb[l15 * 72 + quad * 8]);
        o0 = MFMA16(pa_lo, lds8(Vc + 0 * 512 + lane * 8), o0);
        o1 = MFMA16(pa_lo, lds8(Vc + 2 * 512 + lane * 8), o1);
        o2 = MFMA16(pa_lo, lds8(Vc + 4 * 512 + lane * 8), o2);
        o3 = MFMA16(pa_lo, lds8(Vc + 6 * 512 + lane * 8), o3);
        if (!skipHi) {
            short8 pa_hi = lds8(&pb[l15 * 72 + 32 + quad * 8]);
            o0 = MFMA16(pa_hi, lds8(Vc + 1 * 512 + lane * 8), o0);
            o1 = MFMA16(pa_hi, lds8(Vc + 3 * 512 + lane * 8), o1);
            o2 = MFMA16(pa_hi, lds8(Vc + 5 * 512 + lane * 8), o2);
            o3 = MFMA16(pa_hi, lds8(Vc + 7 * 512 + lane * 8), o3);
        }
    }

    // final per-row l reduction (keys live on l15 lanes)
#pragma unroll
    for (int r = 0; r < 4; ++r) {
        float l = L[r];
#pragma unroll
        for (int off = 8; off >= 1; off >>= 1) l += __shfl_xor(l, off);
        L[r] = l;
    }

    // write O[b][t][h*64+d] bf16, packed dword stores from even lanes
    unsigned short* Ob = O + (size_t)b * 4096 * 2048 + h * 64;
#pragma unroll
    for (int r = 0; r < 4; ++r) {
        const int q = qt0 + quad * 4 + r;
        const float inv = 1.f / L[r];
        float w0 = o0[r] * inv, w1 = o1[r] * inv, w2 = o2[r] * inv, w3 = o3[r] * inv;
        float p0 = __shfl_xor(w0, 1), p1 = __shfl_xor(w1, 1);
        float p2 = __shfl_xor(w2, 1), p3 = __shfl_xor(w3, 1);
        if (!(lane & 1)) {
            unsigned short* op = Ob + (size_t)q * 2048 + l15;
            *reinterpret_cast<unsigned int*>(op)      = (unsigned int)f2bf(w0) | ((unsigned int)f2bf(p0) << 16);
            *reinterpret_cast<unsigned int*>(op + 16) = (unsigned int)f2bf(w1) | ((unsigned int)f2bf(p1) << 16);
            *reinterpret_cast<unsigned int*>(op + 32) = (unsigned int)f2bf(w2) | ((unsigned int)f2bf(p2) << 16);
            *reinterpret_cast<unsigned int*>(op + 48) = (unsigned int)f2bf(w3) | ((unsigned int)f2bf(p3) << 16);
        }
    }
}

// ---------------- launch ----------------
extern "C" void kernel_launch(void* const* d_in, const int* in_sizes, int n_in,
                              void* d_out, int out_size, void* d_ws, size_t ws_size,
                              hipStream_t stream) {
    const float* x  = (const float*)d_in[0];
    const float* kc = (const float*)d_in[1];
    const float* vc = (const float*)d_in[2];
    const float* Wq = (const float*)d_in[3];
    const float* Wo = (const float*)d_in[4];
    float* out = (float*)d_out;

    char* ws = (char*)d_ws;
    unsigned short* Xb  = (unsigned short*)(ws);              // 33,554,432 B (reused as O)
    unsigned short* Qb  = (unsigned short*)(ws + 33554432);   // 33,554,432 B
    unsigned short* Wqb = (unsigned short*)(ws + 67108864);   //  8,388,608 B
    unsigned short* Wob = (unsigned short*)(ws + 75497472);   //  8,388,608 B
    unsigned short* Kwb = (unsigned short*)(ws + 83886080);   //  2,097,152 B
    unsigned short* Vtb = (unsigned short*)(ws + 85983232);   //  2,097,152 B

    cvt_bf16<<<16384, 256, 0, stream>>>(x,  Xb,  4194304);
    cvt_bf16<<<4096,  256, 0, stream>>>(Wq, Wqb, 1048576);
    cvt_bf16<<<4096,  256, 0, stream>>>(Wo, Wob, 1048576);
    prep_k<<<1024, 256, 0, stream>>>(kc, Kwb);
    prep_v<<<256, 256, 0, stream>>>(vc, Vtb);

    gemm_bt<0><<<1024, 256, 0, stream>>>(Xb, Wqb, nullptr, Qb);   // Q + RoPE (pre-scaled)
    attn<<<4096, 256, 0, stream>>>(Qb, Kwb, Vtb, Xb);             // O -> Xb
    gemm_bt<1><<<1024, 256, 0, stream>>>(Xb, Wob, out, nullptr);  // out proj
}